// Round 1
// baseline (1175.385 us; speedup 1.0000x reference)
//
#include <hip/hip_runtime.h>
#include <hip/hip_bf16.h>

#define NNODE 4096
#define DH    128
#define NEDGE 65536

typedef __attribute__((ext_vector_type(8))) short bf16x8;
typedef __attribute__((ext_vector_type(4))) float f32x4;

__device__ __forceinline__ short f2bf(float f) {
  union { float f; unsigned u; } v; v.f = f;
  unsigned r = v.u + 0x7FFFu + ((v.u >> 16) & 1u);
  return (short)(r >> 16);
}

__device__ __forceinline__ float dot4(float4 a, float4 b) {
  return a.x*b.x + a.y*b.y + a.z*b.z + a.w*b.w;
}

// ---------------- small utility kernels ----------------

__global__ void k_fill(float* __restrict__ p, float v, int n) {
  int i = blockIdx.x * 256 + threadIdx.x;
  if (i < n) p[i] = v;
}

__global__ void k_count(const int* __restrict__ dst, float* __restrict__ cnt) {
  int e = blockIdx.x * 256 + threadIdx.x;
  if (e < NEDGE) atomicAdd(&cnt[dst[e]], 1.0f);
}

// Y[i][o] = relu(X[i]·W[o] + b[o]), Dout = 128, Din in {64,128}
__global__ void k_linear_relu(const float* __restrict__ X, const float* __restrict__ W,
                              const float* __restrict__ b, float* __restrict__ Y, int Din) {
  int idx = blockIdx.x * 256 + threadIdx.x;   // NNODE*128 total
  int i = idx >> 7, o = idx & 127;
  const float4* xv = (const float4*)(X + (size_t)i * Din);
  const float4* wv = (const float4*)(W + (size_t)o * Din);
  float acc = 0.f;
  int n4 = Din >> 2;
  for (int k = 0; k < n4; ++k) acc += dot4(xv[k], wv[k]);
  Y[idx] = fmaxf(acc + b[o], 0.f);
}

// Y[i][o] = relu([X1|X2][i]·W[o] + b[o]), W is [128 x 256]
__global__ void k_linear2_relu(const float* __restrict__ X1, const float* __restrict__ X2,
                               const float* __restrict__ W, const float* __restrict__ b,
                               float* __restrict__ Y) {
  int idx = blockIdx.x * 256 + threadIdx.x;
  int i = idx >> 7, o = idx & 127;
  const float4* x1v = (const float4*)(X1 + (size_t)i * 128);
  const float4* x2v = (const float4*)(X2 + (size_t)i * 128);
  const float4* w1  = (const float4*)(W + (size_t)o * 256);
  float acc = 0.f;
  for (int k = 0; k < 32; ++k) acc += dot4(x1v[k], w1[k]);
  for (int k = 0; k < 32; ++k) acc += dot4(x2v[k], w1[32 + k]);
  Y[idx] = fmaxf(acc + b[o], 0.f);
}

// edge-wise scatter add: agg[dst] += H[src]; 2 edges per 256-thread block
__global__ void k_scatter(const float* __restrict__ H, const int* __restrict__ src,
                          const int* __restrict__ dst, float* __restrict__ agg) {
  int e = blockIdx.x * 2 + (threadIdx.x >> 7);
  int d = threadIdx.x & 127;
  int s = src[e], t = dst[e];
  atomicAdd(&agg[(size_t)t * 128 + d], H[(size_t)s * 128 + d]);
}

__global__ void k_finish(float* __restrict__ Y, const float* __restrict__ agg,
                         const float* __restrict__ cnt) {
  int idx = blockIdx.x * 256 + threadIdx.x;
  int i = idx >> 7;
  Y[idx] += agg[idx] / fmaxf(cnt[i], 1.0f);
}

// one wave per row: nrm[i] = max(||X[i]||, 1e-12)
__global__ void k_rownorm(const float* __restrict__ X, float* __restrict__ nrm) {
  int i = blockIdx.x, l = threadIdx.x;      // 64 threads
  float a = X[(size_t)i * 128 + l];
  float b = X[(size_t)i * 128 + 64 + l];
  float s = a * a + b * b;
  for (int off = 32; off > 0; off >>= 1) s += __shfl_down(s, off);
  if (l == 0) nrm[i] = fmaxf(sqrtf(s), 1e-12f);
}

__global__ void k_normed_bf16(const float* __restrict__ X, const float* __restrict__ nrm,
                              short* __restrict__ Yb) {
  int idx = blockIdx.x * 256 + threadIdx.x;
  int i = idx >> 7;
  Yb[idx] = f2bf(X[idx] / nrm[i]);
}

// G[j][d] = bf16( (x[j] · A[d]) / nrm[j] )   (A is [128x128] row-major)
__global__ void k_compute_G(const float* __restrict__ X, const float* __restrict__ nrm,
                            const float* __restrict__ Amat, short* __restrict__ Gb) {
  int idx = blockIdx.x * 256 + threadIdx.x;
  int j = idx >> 7, d = idx & 127;
  const float4* xv = (const float4*)(X + (size_t)j * 128);
  const float4* av = (const float4*)(Amat + (size_t)d * 128);
  float acc = 0.f;
  for (int k = 0; k < 32; ++k) acc += dot4(xv[k], av[k]);
  Gb[idx] = f2bf(acc / nrm[j]);
}

// ---------------- affinity: M0 = exp(min(F1·F2^T / 16384, 85)) ----------------
// NT bf16 MFMA GEMM, 64x64 tile per 256-thread block, K=128 fully staged in LDS.
__global__ __launch_bounds__(256) void k_affinity(const short* __restrict__ F1,
                                                  const short* __restrict__ F2,
                                                  float* __restrict__ M0) {
  __shared__ short lA[64 * 136];   // pad 128 -> 136 (272B rows, 16B aligned, 2-way banks)
  __shared__ short lB[64 * 136];
  int i0 = blockIdx.y * 64, j0 = blockIdx.x * 64;
  int t = threadIdx.x;
  for (int rep = 0; rep < 4; ++rep) {
    int chunk = rep * 256 + t;          // 1024 chunks of 8 bf16
    int row = chunk >> 4, c8 = (chunk & 15) * 8;
    *(bf16x8*)&lA[row * 136 + c8] = *(const bf16x8*)&F1[(size_t)(i0 + row) * 128 + c8];
    *(bf16x8*)&lB[row * 136 + c8] = *(const bf16x8*)&F2[(size_t)(j0 + row) * 128 + c8];
  }
  __syncthreads();
  int w = t >> 6, l = t & 63;
  int ar = w * 16 + (l & 15);
  int kb = (l >> 4) * 8;
  f32x4 acc[4] = {};
  for (int kk = 0; kk < 4; ++kk) {
    bf16x8 a = *(const bf16x8*)&lA[ar * 136 + kk * 32 + kb];
    for (int nt = 0; nt < 4; ++nt) {
      bf16x8 bb = *(const bf16x8*)&lB[(nt * 16 + (l & 15)) * 136 + kk * 32 + kb];
      acc[nt] = __builtin_amdgcn_mfma_f32_16x16x32_bf16(a, bb, acc[nt], 0, 0, 0);
    }
  }
  const float INV = 1.0f / 16384.0f;
  int ro = (l >> 4) * 4;
  for (int nt = 0; nt < 4; ++nt)
    for (int q = 0; q < 4; ++q) {
      int i = i0 + w * 16 + ro + q;
      int j = j0 + nt * 16 + (l & 15);
      float v = fminf(acc[nt][q] * INV, 85.0f);
      M0[(size_t)i * 4096 + j] = __expf(v);
    }
}

// ---------------- sinkhorn matvecs on implicit diag(r) M0 diag(c) ----------------

// s_i = dot(M0[i], c);  r[i] <- r[i] / max(r[i]*s_i, 1e-6)
__global__ void k_rowmv(const float* __restrict__ M0, const float* __restrict__ cv,
                        float* __restrict__ rv) {
  int i = blockIdx.x, t = threadIdx.x;   // 256 threads
  const float4* Mv = (const float4*)(M0 + (size_t)i * 4096);
  const float4* cc = (const float4*)cv;
  float s = 0.f;
  for (int m = 0; m < 4; ++m) s += dot4(Mv[t + 256 * m], cc[t + 256 * m]);
  for (int off = 32; off > 0; off >>= 1) s += __shfl_down(s, off);
  __shared__ float red[4];
  if ((t & 63) == 0) red[t >> 6] = s;
  __syncthreads();
  if (t == 0) {
    float tot = red[0] + red[1] + red[2] + red[3];
    float r0 = rv[i];
    rv[i] = r0 / fmaxf(r0 * tot, 1e-6f);
  }
}

// u[j] += sum over block's 64 rows of M0[i][j]*r[i]   (u pre-zeroed)
__global__ void k_colmv(const float* __restrict__ M0, const float* __restrict__ rv,
                        float* __restrict__ u) {
  int b = blockIdx.x, t = threadIdx.x;   // 64 blocks x 256 threads
  float4 acc[4] = {};
  for (int ii = 0; ii < 64; ++ii) {
    int i = b * 64 + ii;
    float r0 = rv[i];
    const float4* Mv = (const float4*)(M0 + (size_t)i * 4096);
    for (int m = 0; m < 4; ++m) {
      float4 a = Mv[t + 256 * m];
      acc[m].x += a.x * r0; acc[m].y += a.y * r0;
      acc[m].z += a.z * r0; acc[m].w += a.w * r0;
    }
  }
  for (int m = 0; m < 4; ++m) {
    int j = (t + 256 * m) * 4;
    atomicAdd(&u[j + 0], acc[m].x); atomicAdd(&u[j + 1], acc[m].y);
    atomicAdd(&u[j + 2], acc[m].z); atomicAdd(&u[j + 3], acc[m].w);
  }
}

__global__ void k_cupdate(float* __restrict__ c, const float* __restrict__ u) {
  int j = blockIdx.x * 256 + threadIdx.x;
  if (j < 4096) {
    float cv = c[j];
    c[j] = cv / fmaxf(cv * u[j], 1e-6f);
  }
}

// ---------------- 64x64 f32 transpose ----------------
__global__ void k_transpose(const float* __restrict__ A, float* __restrict__ AT) {
  __shared__ float tile[64][65];
  int bx = blockIdx.x, by = blockIdx.y;
  int t = threadIdx.x;
  int colb = t & 63, rowg = t >> 6;
  for (int rr = 0; rr < 16; ++rr) {
    int row = rowg * 16 + rr;
    tile[row][colb] = A[(size_t)(by * 64 + row) * 4096 + bx * 64 + colb];
  }
  __syncthreads();
  for (int rr = 0; rr < 16; ++rr) {
    int row = rowg * 16 + rr;
    AT[(size_t)(bx * 64 + row) * 4096 + by * 64 + colb] = tile[colb][row];
  }
}

// XT[d][j] = bf16(scale[j] * X[j][d]); per-block 64 j rows, all 128 d
__global__ void k_build_xT(const float* __restrict__ X, const float* __restrict__ scale,
                           short* __restrict__ XT) {
  __shared__ short lt[64 * 136];
  int j0 = blockIdx.x * 64;
  int t = threadIdx.x;
  for (int rep = 0; rep < 32; ++rep) {
    int idx = rep * 256 + t;           // 8192 elems
    int j = idx >> 7, d = idx & 127;
    lt[j * 136 + d] = f2bf(X[(size_t)(j0 + j) * 128 + d] * scale[j0 + j]);
  }
  __syncthreads();
  for (int rep = 0; rep < 32; ++rep) {
    int idx = rep * 256 + t;
    int d = idx >> 6, jj = idx & 63;
    XT[(size_t)d * 4096 + j0 + jj] = lt[jj * 136 + d];
  }
}

// Y[m][d] += rs[m] * sum_k A[m][k] * BT[d][k]   (A f32 4096x4096 row-major, BT bf16 128x4096)
// grid (64 m-tiles, 8 k-splits); Y pre-zeroed, atomic accumulate.
__global__ __launch_bounds__(256) void k_m0x(const float* __restrict__ A,
                                             const short* __restrict__ BT,
                                             const float* __restrict__ rs,
                                             float* __restrict__ Y) {
  int m0 = blockIdx.x * 64;
  int k0base = blockIdx.y * 512;
  int w = threadIdx.x >> 6, l = threadIdx.x & 63;
  int row = m0 + w * 16 + (l & 15);
  int kloc = (l >> 4) * 8;
  f32x4 acc[8] = {};
  const float* ap0 = A + (size_t)row * 4096 + kloc;
  for (int k0 = k0base; k0 < k0base + 512; k0 += 32) {
    const float* ap = ap0 + k0;
    float4 x = *(const float4*)ap;
    float4 y = *(const float4*)(ap + 4);
    bf16x8 a;
    a[0] = f2bf(x.x); a[1] = f2bf(x.y); a[2] = f2bf(x.z); a[3] = f2bf(x.w);
    a[4] = f2bf(y.x); a[5] = f2bf(y.y); a[6] = f2bf(y.z); a[7] = f2bf(y.w);
    for (int nt = 0; nt < 8; ++nt) {
      bf16x8 bb = *(const bf16x8*)(BT + (size_t)(nt * 16 + (l & 15)) * 4096 + k0 + kloc);
      acc[nt] = __builtin_amdgcn_mfma_f32_16x16x32_bf16(a, bb, acc[nt], 0, 0, 0);
    }
  }
  for (int nt = 0; nt < 8; ++nt)
    for (int q = 0; q < 4; ++q) {
      int m = m0 + w * 16 + (l >> 4) * 4 + q;
      int d = nt * 16 + (l & 15);
      atomicAdd(&Y[(size_t)m * 128 + d], acc[nt][q] * rs[m]);
    }
}

// out[i][j] = r[i]*c[j]*M0[i][j]
__global__ void k_finalize(const float* __restrict__ M0, const float* __restrict__ r,
                           const float* __restrict__ c, float* __restrict__ out) {
  size_t idx = (size_t)blockIdx.x * 256 + threadIdx.x;   // 4096*1024 float4s
  int i = (int)(idx >> 10);
  int j4 = (int)(idx & 1023);
  float4 m = ((const float4*)M0)[idx];
  float4 cv = ((const float4*)c)[j4];
  float rv = r[i];
  float4 o;
  o.x = m.x * rv * cv.x; o.y = m.y * rv * cv.y;
  o.z = m.z * rv * cv.z; o.w = m.w * rv * cv.w;
  ((float4*)out)[idx] = o;
}

// ---------------- host ----------------

extern "C" void kernel_launch(void* const* d_in, const int* in_sizes, int n_in,
                              void* d_out, int out_size, void* d_ws, size_t ws_size,
                              hipStream_t stream) {
  (void)in_sizes; (void)n_in; (void)out_size; (void)ws_size;
  const float* x1 = (const float*)d_in[0];
  const float* x2 = (const float*)d_in[1];
  const int* e1 = (const int*)d_in[2];
  const int* e2 = (const int*)d_in[3];
  const float* g11_Wm = (const float*)d_in[4];
  const float* g11_bm = (const float*)d_in[5];
  const float* g11_Wn = (const float*)d_in[6];
  const float* g11_bn = (const float*)d_in[7];
  const float* g12_Wm = (const float*)d_in[8];
  const float* g12_bm = (const float*)d_in[9];
  const float* g12_Wn = (const float*)d_in[10];
  const float* g12_bn = (const float*)d_in[11];
  const float* aff1_A = (const float*)d_in[12];
  const float* cc1_W  = (const float*)d_in[13];
  const float* cc1_b  = (const float*)d_in[14];
  const float* cc2_W  = (const float*)d_in[15];
  const float* cc2_b  = (const float*)d_in[16];
  const float* g21_Wm = (const float*)d_in[17];
  const float* g21_bm = (const float*)d_in[18];
  const float* g21_Wn = (const float*)d_in[19];
  const float* g21_bn = (const float*)d_in[20];
  const float* g22_Wm = (const float*)d_in[21];
  const float* g22_bm = (const float*)d_in[22];
  const float* g22_Wn = (const float*)d_in[23];
  const float* g22_bn = (const float*)d_in[24];
  const float* aff2_A = (const float*)d_in[25];

  char* ws = (char*)d_ws;
  size_t off = 0;
  auto alloc = [&](size_t bytes) -> char* {
    char* p = ws + off;
    off = (off + bytes + 255) & ~(size_t)255;
    return p;
  };
  float* M0   = (float*)alloc((size_t)4096 * 4096 * 4);
  float* x1_1 = (float*)alloc((size_t)4096 * 128 * 4);
  float* x2_1 = (float*)alloc((size_t)4096 * 128 * 4);
  float* x1_2 = (float*)alloc((size_t)4096 * 128 * 4);
  float* x2_2 = (float*)alloc((size_t)4096 * 128 * 4);
  float* x1_3 = (float*)alloc((size_t)4096 * 128 * 4);
  float* x2_3 = (float*)alloc((size_t)4096 * 128 * 4);
  float* Hm   = (float*)alloc((size_t)4096 * 128 * 4);
  float* agg  = (float*)alloc((size_t)4096 * 128 * 4);
  float* Cbuf = (float*)alloc((size_t)4096 * 128 * 4);
  short* f1b  = (short*)alloc((size_t)4096 * 128 * 2);
  short* Gb   = (short*)alloc((size_t)4096 * 128 * 2);
  short* XT   = (short*)alloc((size_t)128 * 4096 * 2);
  float* cnt1 = (float*)alloc(4096 * 4);
  float* cnt2 = (float*)alloc(4096 * 4);
  float* nrm1 = (float*)alloc(4096 * 4);
  float* nrm2 = (float*)alloc(4096 * 4);
  float* rvec = (float*)alloc(4096 * 4);
  float* cvec = (float*)alloc(4096 * 4);
  float* uvec = (float*)alloc(4096 * 4);

  auto gconv = [&](const float* X, const int* edge, const float* Wm, const float* bm,
                   const float* Wn, const float* bn, const float* cnt, float* Y, int Din) {
    k_linear_relu<<<2048, 256, 0, stream>>>(X, Wm, bm, Hm, Din);
    hipMemsetAsync(agg, 0, (size_t)4096 * 128 * 4, stream);
    k_scatter<<<32768, 256, 0, stream>>>(Hm, edge, edge + NEDGE, agg);
    k_linear_relu<<<2048, 256, 0, stream>>>(X, Wn, bn, Y, Din);
    k_finish<<<2048, 256, 0, stream>>>(Y, agg, cnt);
  };

  auto affinity = [&](const float* Xa, const float* Xb, const float* Amat) {
    k_rownorm<<<4096, 64, 0, stream>>>(Xa, nrm1);
    k_rownorm<<<4096, 64, 0, stream>>>(Xb, nrm2);
    k_normed_bf16<<<2048, 256, 0, stream>>>(Xa, nrm1, f1b);
    k_compute_G<<<2048, 256, 0, stream>>>(Xb, nrm2, Amat, Gb);
    dim3 g(64, 64);
    k_affinity<<<g, 256, 0, stream>>>(f1b, Gb, M0);
  };

  auto sinkhorn = [&]() {
    k_fill<<<16, 256, 0, stream>>>(rvec, 1.0f, 4096);
    k_fill<<<16, 256, 0, stream>>>(cvec, 1.0f, 4096);
    for (int it = 0; it < 5; ++it) {
      k_rowmv<<<4096, 256, 0, stream>>>(M0, cvec, rvec);
      hipMemsetAsync(uvec, 0, 4096 * 4, stream);
      k_colmv<<<64, 256, 0, stream>>>(M0, rvec, uvec);
      k_cupdate<<<16, 256, 0, stream>>>(cvec, uvec);
    }
  };

  // counts (shared by both gconv layers per graph)
  hipMemsetAsync(cnt1, 0, 4096 * 4, stream);
  hipMemsetAsync(cnt2, 0, 4096 * 4, stream);
  k_count<<<256, 256, 0, stream>>>(e1 + NEDGE, cnt1);
  k_count<<<256, 256, 0, stream>>>(e2 + NEDGE, cnt2);

  // layer 1
  gconv(x1, e1, g11_Wm, g11_bm, g11_Wn, g11_bn, cnt1, x1_1, 64);
  gconv(x2, e2, g12_Wm, g12_bm, g12_Wn, g12_bn, cnt2, x2_1, 64);

  // affinity 1 + sinkhorn 1
  affinity(x1_1, x2_1, aff1_A);
  sinkhorn();

  // cross conv: C1 = r ⊙ (M0 @ (c ⊙ x2_1)); C2 = c ⊙ (M0^T @ (r ⊙ x1_1))
  float* M0T = (float*)d_out;             // d_out as scratch; overwritten by finalize
  dim3 gt(64, 64);
  k_transpose<<<gt, 256, 0, stream>>>(M0, M0T);

  dim3 gm(64, 8);
  k_build_xT<<<64, 256, 0, stream>>>(x2_1, cvec, XT);
  hipMemsetAsync(Cbuf, 0, (size_t)4096 * 128 * 4, stream);
  k_m0x<<<gm, 256, 0, stream>>>(M0, XT, rvec, Cbuf);
  k_linear2_relu<<<2048, 256, 0, stream>>>(x1_1, Cbuf, cc1_W, cc1_b, x1_2);

  k_build_xT<<<64, 256, 0, stream>>>(x1_1, rvec, XT);
  hipMemsetAsync(Cbuf, 0, (size_t)4096 * 128 * 4, stream);
  k_m0x<<<gm, 256, 0, stream>>>(M0T, XT, cvec, Cbuf);
  k_linear2_relu<<<2048, 256, 0, stream>>>(x2_1, Cbuf, cc2_W, cc2_b, x2_2);

  // layer 2
  gconv(x1_2, e1, g21_Wm, g21_bm, g21_Wn, g21_bn, cnt1, x1_3, 128);
  gconv(x2_2, e2, g22_Wm, g22_bm, g22_Wn, g22_bn, cnt2, x2_3, 128);

  // affinity 2 + sinkhorn 2 + output
  affinity(x1_3, x2_3, aff2_A);
  sinkhorn();
  k_finalize<<<16384, 256, 0, stream>>>(M0, rvec, cvec, (float*)d_out);
}

// Round 2
// 634.856 us; speedup vs baseline: 1.8514x; 1.8514x over previous
//
#include <hip/hip_runtime.h>
#include <hip/hip_bf16.h>

#define NNODE 4096
#define DH    128
#define NEDGE 65536

typedef __attribute__((ext_vector_type(8))) short bf16x8;
typedef __attribute__((ext_vector_type(4))) float f32x4;

__device__ __forceinline__ short f2bf(float f) {
  union { float f; unsigned u; } v; v.f = f;
  unsigned r = v.u + 0x7FFFu + ((v.u >> 16) & 1u);
  return (short)(r >> 16);
}
__device__ __forceinline__ float bf2f(short s) {
  union { unsigned u; float f; } v; v.u = ((unsigned)(unsigned short)s) << 16;
  return v.f;
}
__device__ __forceinline__ float dot4(float4 a, float4 b) {
  return a.x*b.x + a.y*b.y + a.z*b.z + a.w*b.w;
}

// ---------------- small utility kernels ----------------

__global__ void k_fill(float* __restrict__ p, float v, int n) {
  int i = blockIdx.x * 256 + threadIdx.x;
  if (i < n) p[i] = v;
}

__global__ void k_count(const int* __restrict__ dst, float* __restrict__ cnt) {
  int e = blockIdx.x * 256 + threadIdx.x;
  if (e < NEDGE) atomicAdd(&cnt[dst[e]], 1.0f);
}

// edge-wise scatter add: agg[dst] += H[src]; 2 edges per 256-thread block
__global__ void k_scatter(const float* __restrict__ H, const int* __restrict__ src,
                          const int* __restrict__ dst, float* __restrict__ agg) {
  int e = blockIdx.x * 2 + (threadIdx.x >> 7);
  int d = threadIdx.x & 127;
  int s = src[e], t = dst[e];
  atomicAdd(&agg[(size_t)t * 128 + d], H[(size_t)s * 128 + d]);
}

__global__ void k_finish(float* __restrict__ Y, const float* __restrict__ agg,
                         const float* __restrict__ cnt) {
  int idx = blockIdx.x * 256 + threadIdx.x;
  int i = idx >> 7;
  Y[idx] += agg[idx] / fmaxf(cnt[i], 1.0f);
}

// one wave per row: inv[i] = 1/max(||X[i]||, 1e-12)
__global__ void k_rownorm(const float* __restrict__ X, float* __restrict__ inv) {
  int i = blockIdx.x, l = threadIdx.x;      // 64 threads
  float a = X[(size_t)i * 128 + l];
  float b = X[(size_t)i * 128 + 64 + l];
  float s = a * a + b * b;
  for (int off = 32; off > 0; off >>= 1) s += __shfl_down(s, off);
  if (l == 0) inv[i] = 1.0f / fmaxf(sqrtf(s), 1e-12f);
}

__global__ void k_normed_bf16(const float* __restrict__ X, const float* __restrict__ inv,
                              short* __restrict__ Yb) {
  int idx = blockIdx.x * 256 + threadIdx.x;
  Yb[idx] = f2bf(X[idx] * inv[idx >> 7]);
}

// ---------------- generic MFMA linear: Y[4096x128] = act(X @ W^T + b) ----------------
// X staged+converted to bf16 in LDS (optionally row-scaled); W [128 x DIN] f32.
// TWO: X = [X1 | X2] concat (each stride 128). Writes Yf (f32) and/or Yb (bf16).
template<int DIN, bool TWO, bool RELU>
__global__ __launch_bounds__(256) void k_lin(const float* __restrict__ X1,
                                             const float* __restrict__ X2,
                                             const float* __restrict__ W,
                                             const float* __restrict__ bias,
                                             const float* __restrict__ rowscale,
                                             float* __restrict__ Yf,
                                             short* __restrict__ Yb) {
  constexpr int KC  = (DIN > 128) ? 128 : DIN;
  constexpr int NCH = DIN / KC;
  constexpr int LDR = KC + 8;                 // pad: 2-way banks (free), 16B-aligned rows
  __shared__ short lX[64 * LDR];
  __shared__ short lW[128 * LDR];
  int row0 = blockIdx.x * 64;
  int t = threadIdx.x;
  int w = t >> 6, l = t & 63;
  f32x4 acc[8] = {};
  for (int ch = 0; ch < NCH; ++ch) {
    const float* Xs = (TWO && ch == 1) ? X2 : X1;
    const int xstride = TWO ? 128 : DIN;
    for (int idx = t * 4; idx < 64 * KC; idx += 1024) {
      int r = idx / KC, c = idx % KC;
      float4 v = *(const float4*)&Xs[(size_t)(row0 + r) * xstride + c];
      float sc = rowscale ? rowscale[row0 + r] : 1.0f;
      short4 o = { f2bf(v.x * sc), f2bf(v.y * sc), f2bf(v.z * sc), f2bf(v.w * sc) };
      *(short4*)&lX[r * LDR + c] = o;
    }
    for (int idx = t * 4; idx < 128 * KC; idx += 1024) {
      int r = idx / KC, c = idx % KC;
      float4 v = *(const float4*)&W[(size_t)r * DIN + ch * KC + c];
      short4 o = { f2bf(v.x), f2bf(v.y), f2bf(v.z), f2bf(v.w) };
      *(short4*)&lW[r * LDR + c] = o;
    }
    __syncthreads();
    int ar = w * 16 + (l & 15);
    int kb = (l >> 4) * 8;
    for (int kk = 0; kk < KC / 32; ++kk) {
      bf16x8 a = *(const bf16x8*)&lX[ar * LDR + kk * 32 + kb];
      for (int nt = 0; nt < 8; ++nt) {
        bf16x8 b = *(const bf16x8*)&lW[(nt * 16 + (l & 15)) * LDR + kk * 32 + kb];
        acc[nt] = __builtin_amdgcn_mfma_f32_16x16x32_bf16(a, b, acc[nt], 0, 0, 0);
      }
    }
    if (ch + 1 < NCH) __syncthreads();
  }
  int orow0 = row0 + w * 16 + ((l >> 4) << 2);
  int col0 = l & 15;
  for (int nt = 0; nt < 8; ++nt) {
    int col = nt * 16 + col0;
    float bv = bias ? bias[col] : 0.0f;
    for (int q = 0; q < 4; ++q) {
      float v = acc[nt][q] + bv;
      if (RELU) v = fmaxf(v, 0.0f);
      size_t o = (size_t)(orow0 + q) * 128 + col;
      if (Yf) Yf[o] = v;
      if (Yb) Yb[o] = f2bf(v);
    }
  }
}

// ---------------- affinity: Mh = bf16(exp(min(F1·F2^T/16384, 85))), + transposed copy ----
__global__ __launch_bounds__(256) void k_affinity(const short* __restrict__ F1,
                                                  const short* __restrict__ F2,
                                                  short* __restrict__ Mh,
                                                  short* __restrict__ MhT) {
  __shared__ short lA[64 * 136];
  __shared__ short lB[64 * 136];
  __shared__ short lT[64 * 72];
  __shared__ short lTt[64 * 72];
  int i0 = blockIdx.y * 64, j0 = blockIdx.x * 64;
  int t = threadIdx.x;
  for (int rep = 0; rep < 4; ++rep) {
    int chunk = rep * 256 + t;
    int row = chunk >> 4, c8 = (chunk & 15) * 8;
    *(bf16x8*)&lA[row * 136 + c8] = *(const bf16x8*)&F1[(size_t)(i0 + row) * 128 + c8];
    *(bf16x8*)&lB[row * 136 + c8] = *(const bf16x8*)&F2[(size_t)(j0 + row) * 128 + c8];
  }
  __syncthreads();
  int w = t >> 6, l = t & 63;
  int ar = w * 16 + (l & 15);
  int kb = (l >> 4) * 8;
  f32x4 acc[4] = {};
  for (int kk = 0; kk < 4; ++kk) {
    bf16x8 a = *(const bf16x8*)&lA[ar * 136 + kk * 32 + kb];
    for (int nt = 0; nt < 4; ++nt) {
      bf16x8 bb = *(const bf16x8*)&lB[(nt * 16 + (l & 15)) * 136 + kk * 32 + kb];
      acc[nt] = __builtin_amdgcn_mfma_f32_16x16x32_bf16(a, bb, acc[nt], 0, 0, 0);
    }
  }
  const float INV = 1.0f / 16384.0f;
  int ro = (l >> 4) * 4;
  for (int nt = 0; nt < 4; ++nt)
    for (int q = 0; q < 4; ++q) {
      int ri = w * 16 + ro + q;
      int cj = nt * 16 + (l & 15);
      short bv = f2bf(__expf(fminf(acc[nt][q] * INV, 85.0f)));
      lT[ri * 72 + cj] = bv;
      lTt[cj * 72 + ri] = bv;
    }
  __syncthreads();
  for (int rep = 0; rep < 2; ++rep) {
    int idx = rep * 256 + t;              // 512 chunks of 8 bf16
    int rr = idx >> 3, c8 = (idx & 7) * 8;
    *(bf16x8*)&Mh [(size_t)(i0 + rr) * 4096 + j0 + c8] = *(const bf16x8*)&lT [rr * 72 + c8];
    *(bf16x8*)&MhT[(size_t)(j0 + rr) * 4096 + i0 + c8] = *(const bf16x8*)&lTt[rr * 72 + c8];
  }
}

// ---------------- sinkhorn: one row-reduction, vout[i] /= max(vout[i]*dot(Mh[i],vin),eps)
__global__ void k_rsum(const short* __restrict__ Mh, const float* __restrict__ vin,
                       float* __restrict__ vout) {
  int i = blockIdx.x, t = threadIdx.x;   // 256 threads
  const short* row = Mh + (size_t)i * 4096;
  float s = 0.0f;
  for (int m = 0; m < 2; ++m) {
    int base = (t + 256 * m) * 8;
    bf16x8 v = *(const bf16x8*)&row[base];
    const float4* cc = (const float4*)&vin[base];
    float4 c0 = cc[0], c1 = cc[1];
    s += bf2f(v[0])*c0.x + bf2f(v[1])*c0.y + bf2f(v[2])*c0.z + bf2f(v[3])*c0.w
       + bf2f(v[4])*c1.x + bf2f(v[5])*c1.y + bf2f(v[6])*c1.z + bf2f(v[7])*c1.w;
  }
  for (int off = 32; off > 0; off >>= 1) s += __shfl_down(s, off);
  __shared__ float red[4];
  if ((t & 63) == 0) red[t >> 6] = s;
  __syncthreads();
  if (t == 0) {
    float tot = red[0] + red[1] + red[2] + red[3];
    float v0 = vout[i];
    vout[i] = v0 / fmaxf(v0 * tot, 1e-6f);
  }
}

// XT[d][j] = bf16(scale[j] * X[j][d]); per-block 64 j rows, all 128 d
__global__ void k_build_xT(const float* __restrict__ X, const float* __restrict__ scale,
                           short* __restrict__ XT) {
  __shared__ short lt[64 * 136];
  int j0 = blockIdx.x * 64;
  int t = threadIdx.x;
  for (int rep = 0; rep < 32; ++rep) {
    int idx = rep * 256 + t;           // 8192 elems
    int j = idx >> 7, d = idx & 127;
    lt[j * 136 + d] = f2bf(X[(size_t)(j0 + j) * 128 + d] * scale[j0 + j]);
  }
  __syncthreads();
  for (int rep = 0; rep < 32; ++rep) {
    int idx = rep * 256 + t;
    int d = idx >> 6, jj = idx & 63;
    XT[(size_t)d * 4096 + j0 + jj] = lt[jj * 136 + d];
  }
}

// Y[m][d] += rs[m] * sum_k A[m][k]*BT[d][k]  (A bf16 4096x4096, BT bf16 128x4096)
// grid (64 m-tiles, 8 k-splits); Y pre-zeroed, atomic accumulate.
__global__ __launch_bounds__(256) void k_m0x(const short* __restrict__ A,
                                             const short* __restrict__ BT,
                                             const float* __restrict__ rs,
                                             float* __restrict__ Y) {
  int m0 = blockIdx.x * 64;
  int k0base = blockIdx.y * 512;
  int w = threadIdx.x >> 6, l = threadIdx.x & 63;
  int row = m0 + w * 16 + (l & 15);
  int kloc = (l >> 4) * 8;
  f32x4 acc[8] = {};
  const short* ap0 = A + (size_t)row * 4096 + kloc;
  for (int k0 = k0base; k0 < k0base + 512; k0 += 32) {
    bf16x8 a = *(const bf16x8*)(ap0 + k0);
    for (int nt = 0; nt < 8; ++nt) {
      bf16x8 bb = *(const bf16x8*)(BT + (size_t)(nt * 16 + (l & 15)) * 4096 + k0 + kloc);
      acc[nt] = __builtin_amdgcn_mfma_f32_16x16x32_bf16(a, bb, acc[nt], 0, 0, 0);
    }
  }
  for (int nt = 0; nt < 8; ++nt)
    for (int q = 0; q < 4; ++q) {
      int m = m0 + w * 16 + (l >> 4) * 4 + q;
      int d = nt * 16 + (l & 15);
      atomicAdd(&Y[(size_t)m * 128 + d], acc[nt][q] * rs[m]);
    }
}

// out[i][j] = r[i]*c[j]*Mh[i][j]
__global__ void k_finalize(const short* __restrict__ Mh, const float* __restrict__ r,
                           const float* __restrict__ c, float* __restrict__ out) {
  size_t idx = (size_t)blockIdx.x * 256 + threadIdx.x;   // 2M chunks of 8
  int i = (int)(idx >> 9);
  int j8 = (int)(idx & 511) * 8;
  bf16x8 m = *(const bf16x8*)&Mh[(size_t)i * 4096 + j8];
  float rv = r[i];
  const float4* cp = (const float4*)&c[j8];
  float4 c0 = cp[0], c1 = cp[1];
  float4 o0, o1;
  o0.x = bf2f(m[0])*rv*c0.x; o0.y = bf2f(m[1])*rv*c0.y;
  o0.z = bf2f(m[2])*rv*c0.z; o0.w = bf2f(m[3])*rv*c0.w;
  o1.x = bf2f(m[4])*rv*c1.x; o1.y = bf2f(m[5])*rv*c1.y;
  o1.z = bf2f(m[6])*rv*c1.z; o1.w = bf2f(m[7])*rv*c1.w;
  float4* op = (float4*)&out[(size_t)i * 4096 + j8];
  op[0] = o0; op[1] = o1;
}

// ---------------- host ----------------

extern "C" void kernel_launch(void* const* d_in, const int* in_sizes, int n_in,
                              void* d_out, int out_size, void* d_ws, size_t ws_size,
                              hipStream_t stream) {
  (void)in_sizes; (void)n_in; (void)out_size; (void)ws_size;
  const float* x1 = (const float*)d_in[0];
  const float* x2 = (const float*)d_in[1];
  const int* e1 = (const int*)d_in[2];
  const int* e2 = (const int*)d_in[3];
  const float* g11_Wm = (const float*)d_in[4];
  const float* g11_bm = (const float*)d_in[5];
  const float* g11_Wn = (const float*)d_in[6];
  const float* g11_bn = (const float*)d_in[7];
  const float* g12_Wm = (const float*)d_in[8];
  const float* g12_bm = (const float*)d_in[9];
  const float* g12_Wn = (const float*)d_in[10];
  const float* g12_bn = (const float*)d_in[11];
  const float* aff1_A = (const float*)d_in[12];
  const float* cc1_W  = (const float*)d_in[13];
  const float* cc1_b  = (const float*)d_in[14];
  const float* cc2_W  = (const float*)d_in[15];
  const float* cc2_b  = (const float*)d_in[16];
  const float* g21_Wm = (const float*)d_in[17];
  const float* g21_bm = (const float*)d_in[18];
  const float* g21_Wn = (const float*)d_in[19];
  const float* g21_bn = (const float*)d_in[20];
  const float* g22_Wm = (const float*)d_in[21];
  const float* g22_bm = (const float*)d_in[22];
  const float* g22_Wn = (const float*)d_in[23];
  const float* g22_bn = (const float*)d_in[24];
  const float* aff2_A = (const float*)d_in[25];

  char* ws = (char*)d_ws;
  size_t off = 0;
  auto alloc = [&](size_t bytes) -> char* {
    char* p = ws + off;
    off = (off + bytes + 255) & ~(size_t)255;
    return p;
  };
  short* Mh   = (short*)alloc((size_t)4096 * 4096 * 2);
  short* MhT  = (short*)alloc((size_t)4096 * 4096 * 2);
  float* x1_1 = (float*)alloc((size_t)4096 * 128 * 4);
  float* x2_1 = (float*)alloc((size_t)4096 * 128 * 4);
  float* x1_2 = (float*)alloc((size_t)4096 * 128 * 4);
  float* x2_2 = (float*)alloc((size_t)4096 * 128 * 4);
  float* x1_3 = (float*)alloc((size_t)4096 * 128 * 4);
  float* x2_3 = (float*)alloc((size_t)4096 * 128 * 4);
  float* Hm   = (float*)alloc((size_t)4096 * 128 * 4);
  float* agg  = (float*)alloc((size_t)4096 * 128 * 4);
  float* Cbuf = (float*)alloc((size_t)4096 * 128 * 4);
  short* f1b  = (short*)alloc((size_t)4096 * 128 * 2);
  short* Gb   = (short*)alloc((size_t)4096 * 128 * 2);
  short* XT   = (short*)alloc((size_t)128 * 4096 * 2);
  float* cnt1 = (float*)alloc(4096 * 4);
  float* cnt2 = (float*)alloc(4096 * 4);
  float* inv1 = (float*)alloc(4096 * 4);
  float* inv2 = (float*)alloc(4096 * 4);
  float* rvec = (float*)alloc(4096 * 4);
  float* cvec = (float*)alloc(4096 * 4);

  auto gconv64 = [&](const float* X, const int* edge, const float* Wm, const float* bm,
                     const float* Wn, const float* bn, const float* cnt, float* Y) {
    k_lin<64, false, true><<<64, 256, 0, stream>>>(X, nullptr, Wm, bm, nullptr, Hm, nullptr);
    hipMemsetAsync(agg, 0, (size_t)4096 * 128 * 4, stream);
    k_scatter<<<32768, 256, 0, stream>>>(Hm, edge, edge + NEDGE, agg);
    k_lin<64, false, true><<<64, 256, 0, stream>>>(X, nullptr, Wn, bn, nullptr, Y, nullptr);
    k_finish<<<2048, 256, 0, stream>>>(Y, agg, cnt);
  };
  auto gconv128 = [&](const float* X, const int* edge, const float* Wm, const float* bm,
                      const float* Wn, const float* bn, const float* cnt, float* Y) {
    k_lin<128, false, true><<<64, 256, 0, stream>>>(X, nullptr, Wm, bm, nullptr, Hm, nullptr);
    hipMemsetAsync(agg, 0, (size_t)4096 * 128 * 4, stream);
    k_scatter<<<32768, 256, 0, stream>>>(Hm, edge, edge + NEDGE, agg);
    k_lin<128, false, true><<<64, 256, 0, stream>>>(X, nullptr, Wn, bn, nullptr, Y, nullptr);
    k_finish<<<2048, 256, 0, stream>>>(Y, agg, cnt);
  };

  auto affinity = [&](const float* Xa, const float* Xb, const float* Amat) {
    k_rownorm<<<4096, 64, 0, stream>>>(Xa, inv1);
    k_rownorm<<<4096, 64, 0, stream>>>(Xb, inv2);
    k_normed_bf16<<<2048, 256, 0, stream>>>(Xa, inv1, f1b);
    k_lin<128, false, false><<<64, 256, 0, stream>>>(Xb, nullptr, Amat, nullptr, inv2,
                                                     nullptr, Gb);
    dim3 g(64, 64);
    k_affinity<<<g, 256, 0, stream>>>(f1b, Gb, Mh, MhT);
  };

  auto sinkhorn = [&]() {
    k_fill<<<16, 256, 0, stream>>>(rvec, 1.0f, 4096);
    k_fill<<<16, 256, 0, stream>>>(cvec, 1.0f, 4096);
    for (int it = 0; it < 5; ++it) {
      k_rsum<<<4096, 256, 0, stream>>>(Mh, cvec, rvec);
      k_rsum<<<4096, 256, 0, stream>>>(MhT, rvec, cvec);
    }
  };

  // degree counts
  hipMemsetAsync(cnt1, 0, 4096 * 4, stream);
  hipMemsetAsync(cnt2, 0, 4096 * 4, stream);
  k_count<<<256, 256, 0, stream>>>(e1 + NEDGE, cnt1);
  k_count<<<256, 256, 0, stream>>>(e2 + NEDGE, cnt2);

  // layer 1
  gconv64(x1, e1, g11_Wm, g11_bm, g11_Wn, g11_bn, cnt1, x1_1);
  gconv64(x2, e2, g12_Wm, g12_bm, g12_Wn, g12_bn, cnt2, x2_1);

  // affinity 1 + sinkhorn 1
  affinity(x1_1, x2_1, aff1_A);
  sinkhorn();

  // cross conv: x1_2 = relu([x1_1 | r⊙(Mh@(c⊙x2_1))]·cc1_W^T + b)
  dim3 gm(64, 8);
  k_build_xT<<<64, 256, 0, stream>>>(x2_1, cvec, XT);
  hipMemsetAsync(Cbuf, 0, (size_t)4096 * 128 * 4, stream);
  k_m0x<<<gm, 256, 0, stream>>>(Mh, XT, rvec, Cbuf);
  k_lin<256, true, true><<<64, 256, 0, stream>>>(x1_1, Cbuf, cc1_W, cc1_b, nullptr,
                                                 x1_2, nullptr);

  k_build_xT<<<64, 256, 0, stream>>>(x1_1, rvec, XT);
  hipMemsetAsync(Cbuf, 0, (size_t)4096 * 128 * 4, stream);
  k_m0x<<<gm, 256, 0, stream>>>(MhT, XT, cvec, Cbuf);
  k_lin<256, true, true><<<64, 256, 0, stream>>>(x2_1, Cbuf, cc2_W, cc2_b, nullptr,
                                                 x2_2, nullptr);

  // layer 2
  gconv128(x1_2, e1, g21_Wm, g21_bm, g21_Wn, g21_bn, cnt1, x1_3);
  gconv128(x2_2, e2, g22_Wm, g22_bm, g22_Wn, g22_bn, cnt2, x2_3);

  // affinity 2 + sinkhorn 2 + output
  affinity(x1_3, x2_3, aff2_A);
  sinkhorn();
  k_finalize<<<8192, 256, 0, stream>>>(Mh, rvec, cvec, (float*)d_out);
}

// Round 3
// 482.025 us; speedup vs baseline: 2.4384x; 1.3171x over previous
//
#include <hip/hip_runtime.h>
#include <hip/hip_bf16.h>

#define NNODE 4096
#define DH    128
#define NEDGE 65536

typedef __attribute__((ext_vector_type(8))) short bf16x8;
typedef __attribute__((ext_vector_type(4))) float f32x4;

__device__ __forceinline__ short f2bf(float f) {
  union { float f; unsigned u; } v; v.f = f;
  unsigned r = v.u + 0x7FFFu + ((v.u >> 16) & 1u);
  return (short)(r >> 16);
}
__device__ __forceinline__ float bf2f(short s) {
  union { unsigned u; float f; } v; v.u = ((unsigned)(unsigned short)s) << 16;
  return v.f;
}

// ---------------- CSR build ----------------

__global__ void k_count(const int* __restrict__ e1, const int* __restrict__ e2,
                        int* __restrict__ deg) {
  int i = blockIdx.x * 256 + threadIdx.x;       // 131072
  int g = i >> 16, idx = i & (NEDGE - 1);
  const int* dst = (g ? e2 : e1) + NEDGE;
  atomicAdd(&deg[g * 4096 + dst[idx]], 1);
}

// one block per graph: exclusive scan of deg[4096] -> rowstart[4097], cursor[4096]
__global__ void k_scan(const int* __restrict__ deg, int* __restrict__ rowstart,
                       int* __restrict__ cursor) {
  __shared__ int part[256];
  int g = blockIdx.x;
  const int* d = deg + g * 4096;
  int* rs = rowstart + g * 4097;
  int* cu = cursor + g * 4096;
  int t = threadIdx.x;
  int base = t * 16;
  int loc[16];
  int s = 0;
  for (int k = 0; k < 16; ++k) { loc[k] = s; s += d[base + k]; }
  part[t] = s;
  __syncthreads();
  for (int off = 1; off < 256; off <<= 1) {
    int u = (t >= off) ? part[t - off] : 0;
    __syncthreads();
    part[t] += u;
    __syncthreads();
  }
  int excl = part[t] - s;
  for (int k = 0; k < 16; ++k) {
    rs[base + k] = excl + loc[k];
    cu[base + k] = excl + loc[k];
  }
  if (t == 255) rs[4096] = part[255];
}

__global__ void k_fillcsr(const int* __restrict__ e1, const int* __restrict__ e2,
                          int* __restrict__ cursor, int* __restrict__ csr) {
  int i = blockIdx.x * 256 + threadIdx.x;       // 131072
  int g = i >> 16, idx = i & (NEDGE - 1);
  const int* E = g ? e2 : e1;
  int src = E[idx], dst = E[NEDGE + idx];
  int pos = atomicAdd(&cursor[g * 4096 + dst], 1);
  csr[g * NEDGE + pos] = src;
}

// Y[node][d] += mean over incoming edges of H[src][d]
__global__ void k_gather(const float* __restrict__ H, const int* __restrict__ csr,
                         const int* __restrict__ rowstart, float* __restrict__ Y) {
  int node = blockIdx.x * 2 + (threadIdx.x >> 7);
  int d = threadIdx.x & 127;
  int s = rowstart[node], e = rowstart[node + 1];
  float acc = 0.0f;
  for (int p = s; p < e; ++p) acc += H[(size_t)csr[p] * 128 + d];
  if (e > s) Y[(size_t)node * 128 + d] += acc / (float)(e - s);
}

// ---------------- row norms ----------------

// per row: write bf16 normalized row (64 threads per block, 1 row)
__global__ void k_normf(const float* __restrict__ X, short* __restrict__ Yb) {
  int i = blockIdx.x, l = threadIdx.x;
  float a = X[(size_t)i * 128 + l];
  float b = X[(size_t)i * 128 + 64 + l];
  float s = a * a + b * b;
  for (int off = 32; off > 0; off >>= 1) s += __shfl_xor(s, off);
  float inv = 1.0f / fmaxf(sqrtf(s), 1e-12f);
  Yb[(size_t)i * 128 + l] = f2bf(a * inv);
  Yb[(size_t)i * 128 + 64 + l] = f2bf(b * inv);
}

__global__ void k_rownorm(const float* __restrict__ X, float* __restrict__ inv) {
  int i = blockIdx.x, l = threadIdx.x;
  float a = X[(size_t)i * 128 + l];
  float b = X[(size_t)i * 128 + 64 + l];
  float s = a * a + b * b;
  for (int off = 32; off > 0; off >>= 1) s += __shfl_xor(s, off);
  if (l == 0) inv[i] = 1.0f / fmaxf(sqrtf(s), 1e-12f);
}

// ---------------- generic MFMA linear: Y[4096x128] = act(X @ W^T + b) ----------------
template<int DIN, bool TWO, bool RELU>
__global__ __launch_bounds__(256) void k_lin(const float* __restrict__ X1,
                                             const float* __restrict__ X2,
                                             const float* __restrict__ W,
                                             const float* __restrict__ bias,
                                             const float* __restrict__ rowscale,
                                             float* __restrict__ Yf,
                                             short* __restrict__ Yb) {
  constexpr int KC  = (DIN > 128) ? 128 : DIN;
  constexpr int NCH = DIN / KC;
  constexpr int LDR = KC + 8;
  __shared__ short lX[64 * LDR];
  __shared__ short lW[128 * LDR];
  int row0 = blockIdx.x * 64;
  int t = threadIdx.x;
  int w = t >> 6, l = t & 63;
  f32x4 acc[8] = {};
  for (int ch = 0; ch < NCH; ++ch) {
    const float* Xs = (TWO && ch == 1) ? X2 : X1;
    const int xstride = TWO ? 128 : DIN;
    for (int idx = t * 4; idx < 64 * KC; idx += 1024) {
      int r = idx / KC, c = idx % KC;
      float4 v = *(const float4*)&Xs[(size_t)(row0 + r) * xstride + c];
      float sc = rowscale ? rowscale[row0 + r] : 1.0f;
      short4 o = { f2bf(v.x * sc), f2bf(v.y * sc), f2bf(v.z * sc), f2bf(v.w * sc) };
      *(short4*)&lX[r * LDR + c] = o;
    }
    for (int idx = t * 4; idx < 128 * KC; idx += 1024) {
      int r = idx / KC, c = idx % KC;
      float4 v = *(const float4*)&W[(size_t)r * DIN + ch * KC + c];
      short4 o = { f2bf(v.x), f2bf(v.y), f2bf(v.z), f2bf(v.w) };
      *(short4*)&lW[r * LDR + c] = o;
    }
    __syncthreads();
    int ar = w * 16 + (l & 15);
    int kb = (l >> 4) * 8;
    for (int kk = 0; kk < KC / 32; ++kk) {
      bf16x8 a = *(const bf16x8*)&lX[ar * LDR + kk * 32 + kb];
      for (int nt = 0; nt < 8; ++nt) {
        bf16x8 b = *(const bf16x8*)&lW[(nt * 16 + (l & 15)) * LDR + kk * 32 + kb];
        acc[nt] = __builtin_amdgcn_mfma_f32_16x16x32_bf16(a, b, acc[nt], 0, 0, 0);
      }
    }
    if (ch + 1 < NCH) __syncthreads();
  }
  int orow0 = row0 + w * 16 + ((l >> 4) << 2);
  int col0 = l & 15;
  for (int nt = 0; nt < 8; ++nt) {
    int col = nt * 16 + col0;
    float bv = bias ? bias[col] : 0.0f;
    for (int q = 0; q < 4; ++q) {
      float v = acc[nt][q] + bv;
      if (RELU) v = fmaxf(v, 0.0f);
      size_t o = (size_t)(orow0 + q) * 128 + col;
      if (Yf) Yf[o] = v;
      if (Yb) Yb[o] = f2bf(v);
    }
  }
}

// ---------------- affinity: Mh = bf16(exp(min(F1·F2^T/16384, 85))), + transposed copy ----
__global__ __launch_bounds__(256) void k_affinity(const short* __restrict__ F1,
                                                  const short* __restrict__ F2,
                                                  short* __restrict__ Mh,
                                                  short* __restrict__ MhT) {
  __shared__ short lA[64 * 136];
  __shared__ short lB[64 * 136];
  __shared__ short lT[64 * 72];
  __shared__ short lTt[64 * 72];
  int i0 = blockIdx.y * 64, j0 = blockIdx.x * 64;
  int t = threadIdx.x;
  for (int rep = 0; rep < 4; ++rep) {
    int chunk = rep * 256 + t;
    int row = chunk >> 4, c8 = (chunk & 15) * 8;
    *(bf16x8*)&lA[row * 136 + c8] = *(const bf16x8*)&F1[(size_t)(i0 + row) * 128 + c8];
    *(bf16x8*)&lB[row * 136 + c8] = *(const bf16x8*)&F2[(size_t)(j0 + row) * 128 + c8];
  }
  __syncthreads();
  int w = t >> 6, l = t & 63;
  int ar = w * 16 + (l & 15);
  int kb = (l >> 4) * 8;
  f32x4 acc[4] = {};
  for (int kk = 0; kk < 4; ++kk) {
    bf16x8 a = *(const bf16x8*)&lA[ar * 136 + kk * 32 + kb];
    for (int nt = 0; nt < 4; ++nt) {
      bf16x8 bb = *(const bf16x8*)&lB[(nt * 16 + (l & 15)) * 136 + kk * 32 + kb];
      acc[nt] = __builtin_amdgcn_mfma_f32_16x16x32_bf16(a, bb, acc[nt], 0, 0, 0);
    }
  }
  const float INV = 1.0f / 16384.0f;
  int ro = (l >> 4) * 4;
  for (int nt = 0; nt < 4; ++nt)
    for (int q = 0; q < 4; ++q) {
      int ri = w * 16 + ro + q;
      int cj = nt * 16 + (l & 15);
      short bv = f2bf(__expf(fminf(acc[nt][q] * INV, 85.0f)));
      lT[ri * 72 + cj] = bv;
      lTt[cj * 72 + ri] = bv;
    }
  __syncthreads();
  for (int rep = 0; rep < 2; ++rep) {
    int idx = rep * 256 + t;
    int rr = idx >> 3, c8 = (idx & 7) * 8;
    *(bf16x8*)&Mh [(size_t)(i0 + rr) * 4096 + j0 + c8] = *(const bf16x8*)&lT [rr * 72 + c8];
    *(bf16x8*)&MhT[(size_t)(j0 + rr) * 4096 + i0 + c8] = *(const bf16x8*)&lTt[rr * 72 + c8];
  }
}

// ---------------- sinkhorn: one wave per row ----------------
// V1: vin == ones.  VO1: vout == ones on entry.
template<bool V1, bool VO1>
__global__ void k_rsum(const short* __restrict__ Mh, const float* __restrict__ vin,
                       float* __restrict__ vout) {
  int row = blockIdx.x * 4 + (threadIdx.x >> 6);
  int l = threadIdx.x & 63;
  const short* r = Mh + (size_t)row * 4096;
  float s = 0.0f;
  for (int m = 0; m < 8; ++m) {
    int base = (l + 64 * m) * 8;
    bf16x8 v = *(const bf16x8*)&r[base];
    if (V1) {
      s += bf2f(v[0]) + bf2f(v[1]) + bf2f(v[2]) + bf2f(v[3])
         + bf2f(v[4]) + bf2f(v[5]) + bf2f(v[6]) + bf2f(v[7]);
    } else {
      const float4* cc = (const float4*)&vin[base];
      float4 c0 = cc[0], c1 = cc[1];
      s += bf2f(v[0])*c0.x + bf2f(v[1])*c0.y + bf2f(v[2])*c0.z + bf2f(v[3])*c0.w
         + bf2f(v[4])*c1.x + bf2f(v[5])*c1.y + bf2f(v[6])*c1.z + bf2f(v[7])*c1.w;
    }
  }
  for (int off = 32; off > 0; off >>= 1) s += __shfl_xor(s, off);
  if (l == 0) {
    if (VO1) vout[row] = 1.0f / fmaxf(s, 1e-6f);
    else { float v0 = vout[row]; vout[row] = v0 / fmaxf(v0 * s, 1e-6f); }
  }
}

// XT[d][j] = bf16(scale[j] * X[j][d])
__global__ void k_build_xT(const float* __restrict__ X, const float* __restrict__ scale,
                           short* __restrict__ XT) {
  __shared__ short lt[64 * 136];
  int j0 = blockIdx.x * 64;
  int t = threadIdx.x;
  for (int rep = 0; rep < 32; ++rep) {
    int idx = rep * 256 + t;
    int j = idx >> 7, d = idx & 127;
    lt[j * 136 + d] = f2bf(X[(size_t)(j0 + j) * 128 + d] * scale[j0 + j]);
  }
  __syncthreads();
  for (int rep = 0; rep < 32; ++rep) {
    int idx = rep * 256 + t;
    int d = idx >> 6, jj = idx & 63;
    XT[(size_t)d * 4096 + j0 + jj] = lt[jj * 136 + d];
  }
}

// ---------------- M0 @ x : LDS-staged 128x128-tile GEMM, split-K=8 ----------------
// A [4096x4096] bf16, BT [128x4096] bf16; Cpart[split][4096][128] f32.
__global__ __launch_bounds__(256) void k_m0x(const short* __restrict__ A,
                                             const short* __restrict__ BT,
                                             float* __restrict__ Cpart) {
  __shared__ short lA[128 * 72];
  __shared__ short lB[128 * 72];
  int m0 = blockIdx.x * 128;
  int k0 = blockIdx.y * 512;
  int t = threadIdx.x, w = t >> 6, l = t & 63;
  f32x4 acc[2][8] = {};
  for (int ks = 0; ks < 8; ++ks) {
    int kbase = k0 + ks * 64;
    for (int rep = 0; rep < 4; ++rep) {
      int c = rep * 256 + t;               // 1024 chunks of 8 bf16
      int row = c >> 3, c8 = (c & 7) * 8;
      *(bf16x8*)&lA[row * 72 + c8] = *(const bf16x8*)&A[(size_t)(m0 + row) * 4096 + kbase + c8];
      *(bf16x8*)&lB[row * 72 + c8] = *(const bf16x8*)&BT[(size_t)row * 4096 + kbase + c8];
    }
    __syncthreads();
    int kb = (l >> 4) * 8;
    for (int kk = 0; kk < 2; ++kk) {
      bf16x8 a0 = *(const bf16x8*)&lA[(w * 32 + (l & 15)) * 72 + kk * 32 + kb];
      bf16x8 a1 = *(const bf16x8*)&lA[(w * 32 + 16 + (l & 15)) * 72 + kk * 32 + kb];
      for (int nt = 0; nt < 8; ++nt) {
        bf16x8 b = *(const bf16x8*)&lB[(nt * 16 + (l & 15)) * 72 + kk * 32 + kb];
        acc[0][nt] = __builtin_amdgcn_mfma_f32_16x16x32_bf16(a0, b, acc[0][nt], 0, 0, 0);
        acc[1][nt] = __builtin_amdgcn_mfma_f32_16x16x32_bf16(a1, b, acc[1][nt], 0, 0, 0);
      }
    }
    __syncthreads();
  }
  float* cp = Cpart + (size_t)blockIdx.y * (4096 * 128);
  int col = l & 15;
  for (int rf = 0; rf < 2; ++rf)
    for (int nt = 0; nt < 8; ++nt)
      for (int q = 0; q < 4; ++q) {
        int row = m0 + w * 32 + rf * 16 + (l >> 4) * 4 + q;
        cp[(size_t)row * 128 + nt * 16 + col] = acc[rf][nt][q];
      }
}

// Y[m][d] = rs[m] * sum_p Cpart[p][m][d]
__global__ void k_cred(const float* __restrict__ Cpart, const float* __restrict__ rs,
                       float* __restrict__ Y) {
  int idx = blockIdx.x * 256 + threadIdx.x;    // 131072 float4
  float4 s = {0.f, 0.f, 0.f, 0.f};
  for (int p = 0; p < 8; ++p) {
    float4 v = ((const float4*)Cpart)[(size_t)p * 131072 + idx];
    s.x += v.x; s.y += v.y; s.z += v.z; s.w += v.w;
  }
  float r = rs[idx >> 5];
  float4 o = { s.x * r, s.y * r, s.z * r, s.w * r };
  ((float4*)Y)[idx] = o;
}

// out[i][j] = r[i]*c[j]*Mh[i][j]
__global__ void k_finalize(const short* __restrict__ Mh, const float* __restrict__ r,
                           const float* __restrict__ c, float* __restrict__ out) {
  size_t idx = (size_t)blockIdx.x * 256 + threadIdx.x;
  int i = (int)(idx >> 9);
  int j8 = (int)(idx & 511) * 8;
  bf16x8 m = *(const bf16x8*)&Mh[(size_t)i * 4096 + j8];
  float rv = r[i];
  const float4* cp = (const float4*)&c[j8];
  float4 c0 = cp[0], c1 = cp[1];
  float4 o0, o1;
  o0.x = bf2f(m[0])*rv*c0.x; o0.y = bf2f(m[1])*rv*c0.y;
  o0.z = bf2f(m[2])*rv*c0.z; o0.w = bf2f(m[3])*rv*c0.w;
  o1.x = bf2f(m[4])*rv*c1.x; o1.y = bf2f(m[5])*rv*c1.y;
  o1.z = bf2f(m[6])*rv*c1.z; o1.w = bf2f(m[7])*rv*c1.w;
  float4* op = (float4*)&out[(size_t)i * 4096 + j8];
  op[0] = o0; op[1] = o1;
}

// ---------------- host ----------------

extern "C" void kernel_launch(void* const* d_in, const int* in_sizes, int n_in,
                              void* d_out, int out_size, void* d_ws, size_t ws_size,
                              hipStream_t stream) {
  (void)in_sizes; (void)n_in; (void)out_size; (void)ws_size;
  const float* x1 = (const float*)d_in[0];
  const float* x2 = (const float*)d_in[1];
  const int* e1 = (const int*)d_in[2];
  const int* e2 = (const int*)d_in[3];
  const float* g11_Wm = (const float*)d_in[4];
  const float* g11_bm = (const float*)d_in[5];
  const float* g11_Wn = (const float*)d_in[6];
  const float* g11_bn = (const float*)d_in[7];
  const float* g12_Wm = (const float*)d_in[8];
  const float* g12_bm = (const float*)d_in[9];
  const float* g12_Wn = (const float*)d_in[10];
  const float* g12_bn = (const float*)d_in[11];
  const float* aff1_A = (const float*)d_in[12];
  const float* cc1_W  = (const float*)d_in[13];
  const float* cc1_b  = (const float*)d_in[14];
  const float* cc2_W  = (const float*)d_in[15];
  const float* cc2_b  = (const float*)d_in[16];
  const float* g21_Wm = (const float*)d_in[17];
  const float* g21_bm = (const float*)d_in[18];
  const float* g21_Wn = (const float*)d_in[19];
  const float* g21_bn = (const float*)d_in[20];
  const float* g22_Wm = (const float*)d_in[21];
  const float* g22_bm = (const float*)d_in[22];
  const float* g22_Wn = (const float*)d_in[23];
  const float* g22_bn = (const float*)d_in[24];
  const float* aff2_A = (const float*)d_in[25];

  char* ws = (char*)d_ws;
  size_t off = 0;
  auto alloc = [&](size_t bytes) -> char* {
    char* p = ws + off;
    off = (off + bytes + 255) & ~(size_t)255;
    return p;
  };
  short* Mh   = (short*)alloc((size_t)4096 * 4096 * 2);
  short* MhT  = (short*)alloc((size_t)4096 * 4096 * 2);
  float* x1_1 = (float*)alloc((size_t)4096 * 128 * 4);
  float* x2_1 = (float*)alloc((size_t)4096 * 128 * 4);
  float* x1_2 = (float*)alloc((size_t)4096 * 128 * 4);
  float* x2_2 = (float*)alloc((size_t)4096 * 128 * 4);
  float* x1_3 = (float*)alloc((size_t)4096 * 128 * 4);
  float* x2_3 = (float*)alloc((size_t)4096 * 128 * 4);
  float* Hm   = (float*)alloc((size_t)4096 * 128 * 4);
  float* Cbuf = (float*)alloc((size_t)4096 * 128 * 4);
  short* f1b  = (short*)alloc((size_t)4096 * 128 * 2);
  short* Gb   = (short*)alloc((size_t)4096 * 128 * 2);
  short* XT   = (short*)alloc((size_t)128 * 4096 * 2);
  int*   deg  = (int*)alloc(2 * 4096 * 4);
  int*   rowst= (int*)alloc(2 * 4097 * 4);
  int*   curs = (int*)alloc(2 * 4096 * 4);
  int*   csr  = (int*)alloc(2 * NEDGE * 4);
  float* inv2 = (float*)alloc(4096 * 4);
  float* rvec = (float*)alloc(4096 * 4);
  float* cvec = (float*)alloc(4096 * 4);
  float* Cpart = (float*)d_out;               // 16 MB scratch inside 64 MB d_out

  // CSR build (both graphs in shared dispatches)
  hipMemsetAsync(deg, 0, 2 * 4096 * 4, stream);
  k_count<<<512, 256, 0, stream>>>(e1, e2, deg);
  k_scan<<<2, 256, 0, stream>>>(deg, rowst, curs);
  k_fillcsr<<<512, 256, 0, stream>>>(e1, e2, curs, csr);

  auto gconv = [&](const float* X, int g, const float* Wm, const float* bm,
                   const float* Wn, const float* bn, float* Y, bool d64) {
    if (d64) {
      k_lin<64, false, true><<<64, 256, 0, stream>>>(X, nullptr, Wm, bm, nullptr, Hm, nullptr);
      k_lin<64, false, true><<<64, 256, 0, stream>>>(X, nullptr, Wn, bn, nullptr, Y, nullptr);
    } else {
      k_lin<128, false, true><<<64, 256, 0, stream>>>(X, nullptr, Wm, bm, nullptr, Hm, nullptr);
      k_lin<128, false, true><<<64, 256, 0, stream>>>(X, nullptr, Wn, bn, nullptr, Y, nullptr);
    }
    k_gather<<<2048, 256, 0, stream>>>(Hm, csr + g * NEDGE, rowst + g * 4097, Y);
  };

  auto affinity = [&](const float* Xa, const float* Xb, const float* Amat) {
    k_normf<<<4096, 64, 0, stream>>>(Xa, f1b);
    k_rownorm<<<4096, 64, 0, stream>>>(Xb, inv2);
    k_lin<128, false, false><<<64, 256, 0, stream>>>(Xb, nullptr, Amat, nullptr, inv2,
                                                     nullptr, Gb);
    dim3 g(64, 64);
    k_affinity<<<g, 256, 0, stream>>>(f1b, Gb, Mh, MhT);
  };

  auto sinkhorn = [&]() {
    k_rsum<true,  true ><<<1024, 256, 0, stream>>>(Mh,  nullptr, rvec);
    k_rsum<false, true ><<<1024, 256, 0, stream>>>(MhT, rvec,    cvec);
    for (int it = 1; it < 5; ++it) {
      k_rsum<false, false><<<1024, 256, 0, stream>>>(Mh,  cvec, rvec);
      k_rsum<false, false><<<1024, 256, 0, stream>>>(MhT, rvec, cvec);
    }
  };

  // layer 1
  gconv(x1, 0, g11_Wm, g11_bm, g11_Wn, g11_bn, x1_1, true);
  gconv(x2, 1, g12_Wm, g12_bm, g12_Wn, g12_bn, x2_1, true);

  // affinity 1 + sinkhorn 1
  affinity(x1_1, x2_1, aff1_A);
  sinkhorn();

  // cross conv
  dim3 gm(32, 8);
  k_build_xT<<<64, 256, 0, stream>>>(x2_1, cvec, XT);
  k_m0x<<<gm, 256, 0, stream>>>(Mh, XT, Cpart);
  k_cred<<<512, 256, 0, stream>>>(Cpart, rvec, Cbuf);
  k_lin<256, true, true><<<64, 256, 0, stream>>>(x1_1, Cbuf, cc1_W, cc1_b, nullptr,
                                                 x1_2, nullptr);

  k_build_xT<<<64, 256, 0, stream>>>(x1_1, rvec, XT);
  k_m0x<<<gm, 256, 0, stream>>>(MhT, XT, Cpart);
  k_cred<<<512, 256, 0, stream>>>(Cpart, cvec, Cbuf);
  k_lin<256, true, true><<<64, 256, 0, stream>>>(x2_1, Cbuf, cc2_W, cc2_b, nullptr,
                                                 x2_2, nullptr);

  // layer 2
  gconv(x1_2, 0, g21_Wm, g21_bm, g21_Wn, g21_bn, x1_3, false);
  gconv(x2_2, 1, g22_Wm, g22_bm, g22_Wn, g22_bn, x2_3, false);

  // affinity 2 + sinkhorn 2 + output
  affinity(x1_3, x2_3, aff2_A);
  sinkhorn();
  k_finalize<<<8192, 256, 0, stream>>>(Mh, rvec, cvec, (float*)d_out);
}